// Round 10
// baseline (139.904 us; speedup 1.0000x reference)
//
#include <hip/hip_runtime.h>

// Problem constants (from reference setup_inputs)
#define BB 8
#define CC 128
#define HH 128
#define WW 128
#define PLANE (HH * WW)      // 16384
#define KK 9                 // 3x3

// round-to-nearest-even f32 -> bf16 (inputs are finite N(0,1); no NaN path)
__device__ __forceinline__ unsigned short f2bf(float f) {
    unsigned int u = __float_as_uint(f);
    u += 0x7FFFu + ((u >> 16) & 1u);
    return (unsigned short)(u >> 16);
}
__device__ __forceinline__ float bf2f(unsigned short h) {
    return __uint_as_float(((unsigned int)h) << 16);
}

// ---------------------------------------------------------------------------
// Kernel 1: global average pool per (b,c) plane + bf16 staging of x.
// 1024 blocks x 512 threads; each thread sums 8 float4s and writes 8 ushort4s
// (the bf16 copy conv will read: 32 MiB instead of 64 MiB, freshly L3-resident).
// ---------------------------------------------------------------------------
__global__ __launch_bounds__(512) void pool_kernel(const float* __restrict__ x,
                                                   unsigned short* __restrict__ xb,
                                                   float* __restrict__ pooled) {
    int bc = blockIdx.x;
    const float4* p4 = (const float4*)(x + (size_t)bc * PLANE);
    ushort4* q4 = (ushort4*)(xb + (size_t)bc * PLANE);
    int t = threadIdx.x;
    float s = 0.f;
#pragma unroll
    for (int i = 0; i < 8; ++i) {
        float4 v = p4[t + i * 512];
        s += v.x + v.y + v.z + v.w;
        ushort4 q;
        q.x = f2bf(v.x); q.y = f2bf(v.y); q.z = f2bf(v.z); q.w = f2bf(v.w);
        q4[t + i * 512] = q;
    }
#pragma unroll
    for (int off = 32; off > 0; off >>= 1) s += __shfl_down(s, off, 64);
    __shared__ float wsum[8];
    int wave = t >> 6, lane = t & 63;
    if (lane == 0) wsum[wave] = s;
    __syncthreads();
    if (t == 0) {
        float tot = 0.f;
#pragma unroll
        for (int i = 0; i < 8; ++i) tot += wsum[i];
        pooled[bc] = tot * (1.0f / PLANE);
    }
}

// ---------------------------------------------------------------------------
// Kernel 2: kernel generator (tiny, ~3 us).
// 72 blocks x 128 threads; each block redundantly computes h[b,:] in LDS,
// then 128 of the 1152 kern outputs for batch b. All fp32 math.
// ---------------------------------------------------------------------------
__global__ __launch_bounds__(128) void kerngen_kernel(const float* __restrict__ pooled,
                                                      const float* __restrict__ w1,
                                                      const float* __restrict__ b1,
                                                      const float* __restrict__ w2,
                                                      const float* __restrict__ b2,
                                                      float* __restrict__ kern) {
    int b = blockIdx.x / 9;
    int g = blockIdx.x % 9;
    int j = threadIdx.x;
    __shared__ float ps[CC];
    __shared__ float hs[CC];
    ps[j] = pooled[b * CC + j];
    __syncthreads();
    float acc = b1[j];
    const float* w1r = w1 + j * CC;
#pragma unroll 8
    for (int i = 0; i < CC; ++i) acc += ps[i] * w1r[i];
    hs[j] = fmaxf(acc, 0.f);
    __syncthreads();
    int o = g * CC + j;              // [0, 1152)
    float acc2 = b2[o];
    const float* w2r = w2 + o * CC;
#pragma unroll 8
    for (int i = 0; i < CC; ++i) acc2 += hs[i] * w2r[i];
    kern[b * (CC * KK) + o] = acc2;  // layout [b][c*9+p]
}

// ---------------------------------------------------------------------------
// Kernel 3: dynamic depthwise 3x3 conv from the bf16 staged copy.
// 2048 blocks x 256 threads (8 blocks/CU), one half-plane each.
// Each thread: 8-row x 4-col strip. 10 row loads (8 B each, L3-hot bf16),
// halos via width-32 shuffles, 8 coalesced float4 stores. fp32 accumulate.
// ---------------------------------------------------------------------------
__global__ __launch_bounds__(256) void conv_kernel(const unsigned short* __restrict__ xb,
                                                   const float* __restrict__ kern,
                                                   float* __restrict__ out) {
    int bid = blockIdx.x;
    int bc = bid >> 1, half = bid & 1;
    const unsigned short* gplane = xb + (size_t)bc * PLANE;
    float* oplane = out + (size_t)bc * PLANE;
    const float* wp = kern + (size_t)bc * KK;
    float w[9];
#pragma unroll
    for (int p = 0; p < 9; ++p) w[p] = wp[p];

    int t = threadIdx.x;
    int xq = t & 31;               // 4-elem column chunk within the row
    int x0 = xq << 2;
    int yb = half * 64 + (t >> 5) * 8;   // 8 row-groups of 8 rows per half

    // ---- hoisted loads: 10 input rows (yb-1 .. yb+8), 8 B each ----
    float4 cv[10];
#pragma unroll
    for (int si = 0; si < 10; ++si) {
        int yr = yb - 1 + si;
        if (yr >= 0 && yr < HH) {
            ushort4 q = *(const ushort4*)(gplane + yr * WW + x0);
            cv[si] = make_float4(bf2f(q.x), bf2f(q.y), bf2f(q.z), bf2f(q.w));
        } else {
            cv[si] = make_float4(0.f, 0.f, 0.f, 0.f);
        }
    }

    // ---- halos via intra-row shuffles (width 32 isolates row-groups) ----
    float lv[10], rv[10];
#pragma unroll
    for (int si = 0; si < 10; ++si) {
        float lraw = __shfl_up(cv[si].w, 1, 32);
        float rraw = __shfl_down(cv[si].x, 1, 32);
        lv[si] = (xq == 0) ? 0.f : lraw;
        rv[si] = (xq == 31) ? 0.f : rraw;
    }

    // ---- 8 output rows; out[yb+o] uses input rows si = o, o+1, o+2 ----
#pragma unroll
    for (int o = 0; o < 8; ++o) {
        float4 acc = {0.f, 0.f, 0.f, 0.f};
#pragma unroll
        for (int ky = 0; ky < 3; ++ky) {
            int si = o + ky;
            float w0 = w[ky * 3], w1_ = w[ky * 3 + 1], w2_ = w[ky * 3 + 2];
            float4 c = cv[si];
            acc.x += w0 * lv[si] + w1_ * c.x + w2_ * c.y;
            acc.y += w0 * c.x   + w1_ * c.y + w2_ * c.z;
            acc.z += w0 * c.y   + w1_ * c.z + w2_ * c.w;
            acc.w += w0 * c.z   + w1_ * c.w + w2_ * rv[si];
        }
        *(float4*)(oplane + (yb + o) * WW + x0) = acc;
    }
}

// ---------------------------------------------------------------------------
extern "C" void kernel_launch(void* const* d_in, const int* in_sizes, int n_in,
                              void* d_out, int out_size, void* d_ws, size_t ws_size,
                              hipStream_t stream) {
    const float* x  = (const float*)d_in[0];
    const float* w1 = (const float*)d_in[1];
    const float* b1 = (const float*)d_in[2];
    const float* w2 = (const float*)d_in[3];
    const float* b2 = (const float*)d_in[4];
    float* out = (float*)d_out;

    // workspace layout: [xb: 8*128*128*128 ushort = 32 MiB][pooled 1024 f][kern 9216 f]
    unsigned short* xb = (unsigned short*)d_ws;
    float* pooled = (float*)((char*)d_ws + (size_t)BB * CC * PLANE * sizeof(unsigned short));
    float* kern   = pooled + BB * CC;

    pool_kernel<<<BB * CC, 512, 0, stream>>>(x, xb, pooled);
    kerngen_kernel<<<BB * 9, 128, 0, stream>>>(pooled, w1, b1, w2, b2, kern);
    conv_kernel<<<BB * CC * 2, 256, 0, stream>>>(xb, kern, out);
}

// Round 11
// 134.415 us; speedup vs baseline: 1.0408x; 1.0408x over previous
//
#include <hip/hip_runtime.h>

// Problem constants (from reference setup_inputs)
#define BB 8
#define CC 128
#define HH 128
#define WW 128
#define PLANE (HH * WW)      // 16384
#define KK 9                 // 3x3

// ---------------------------------------------------------------------------
// Kernel 1: global average pool per (b,c) plane.
// 1024 blocks x 512 threads; each thread sums 8 float4s. ~11 us (HBM read BW).
// Normal (caching) loads on purpose: x should allocate in L3 for the conv pass.
// ---------------------------------------------------------------------------
__global__ __launch_bounds__(512) void pool_kernel(const float* __restrict__ x,
                                                   float* __restrict__ pooled) {
    int bc = blockIdx.x;
    const float4* p4 = (const float4*)(x + (size_t)bc * PLANE);
    int t = threadIdx.x;
    float s = 0.f;
#pragma unroll
    for (int i = 0; i < 8; ++i) {
        float4 v = p4[t + i * 512];
        s += v.x + v.y + v.z + v.w;
    }
#pragma unroll
    for (int off = 32; off > 0; off >>= 1) s += __shfl_down(s, off, 64);
    __shared__ float wsum[8];
    int wave = t >> 6, lane = t & 63;
    if (lane == 0) wsum[wave] = s;
    __syncthreads();
    if (t == 0) {
        float tot = 0.f;
#pragma unroll
        for (int i = 0; i < 8; ++i) tot += wsum[i];
        pooled[bc] = tot * (1.0f / PLANE);
    }
}

// ---------------------------------------------------------------------------
// Kernel 2: kernel generator (tiny, ~3 us).
// 72 blocks x 128 threads; each block redundantly computes h[b,:] in LDS,
// then 128 of the 1152 kern outputs for batch b. All fp32 math.
// ---------------------------------------------------------------------------
__global__ __launch_bounds__(128) void kerngen_kernel(const float* __restrict__ pooled,
                                                      const float* __restrict__ w1,
                                                      const float* __restrict__ b1,
                                                      const float* __restrict__ w2,
                                                      const float* __restrict__ b2,
                                                      float* __restrict__ kern) {
    int b = blockIdx.x / 9;
    int g = blockIdx.x % 9;
    int j = threadIdx.x;
    __shared__ float ps[CC];
    __shared__ float hs[CC];
    ps[j] = pooled[b * CC + j];
    __syncthreads();
    float acc = b1[j];
    const float* w1r = w1 + j * CC;
#pragma unroll 8
    for (int i = 0; i < CC; ++i) acc += ps[i] * w1r[i];
    hs[j] = fmaxf(acc, 0.f);
    __syncthreads();
    int o = g * CC + j;              // [0, 1152)
    float acc2 = b2[o];
    const float* w2r = w2 + o * CC;
#pragma unroll 8
    for (int i = 0; i < CC; ++i) acc2 += hs[i] * w2r[i];
    kern[b * (CC * KK) + o] = acc2;  // layout [b][c*9+p]
}

// ---------------------------------------------------------------------------
// Kernel 3: dynamic depthwise 3x3 conv, MLP-maximized + non-temporal stores.
// 2048 blocks x 256 threads (8 blocks/CU), one half-plane each.
// Each thread: 8-row x 4-col strip. All 10 row loads hoisted (in flight),
// halos via width-32 shuffles (no extra loads), 8 coalesced float4 NT stores.
// ---------------------------------------------------------------------------
__global__ __launch_bounds__(256) void conv_kernel(const float* __restrict__ x,
                                                   const float* __restrict__ kern,
                                                   float* __restrict__ out) {
    int bid = blockIdx.x;
    int bc = bid >> 1, half = bid & 1;
    const float* gplane = x + (size_t)bc * PLANE;
    float* oplane = out + (size_t)bc * PLANE;
    const float* wp = kern + (size_t)bc * KK;
    float w[9];
#pragma unroll
    for (int p = 0; p < 9; ++p) w[p] = wp[p];

    int t = threadIdx.x;
    int xq = t & 31;               // float4 column chunk within the row
    int x0 = xq << 2;
    int yb = half * 64 + (t >> 5) * 8;   // 8 row-groups of 8 rows per half

    // ---- hoisted loads: 10 input rows (yb-1 .. yb+8), all in flight ----
    float4 cv[10];
#pragma unroll
    for (int si = 0; si < 10; ++si) {
        int yr = yb - 1 + si;
        if (yr >= 0 && yr < HH)
            cv[si] = *(const float4*)(gplane + yr * WW + x0);
        else
            cv[si] = make_float4(0.f, 0.f, 0.f, 0.f);
    }

    // ---- halos via intra-row shuffles (width 32 isolates row-groups) ----
    float lv[10], rv[10];
#pragma unroll
    for (int si = 0; si < 10; ++si) {
        float lraw = __shfl_up(cv[si].w, 1, 32);
        float rraw = __shfl_down(cv[si].x, 1, 32);
        lv[si] = (xq == 0) ? 0.f : lraw;
        rv[si] = (xq == 31) ? 0.f : rraw;
    }

    // ---- 8 output rows; out[yb+o] uses input rows si = o, o+1, o+2 ----
#pragma unroll
    for (int o = 0; o < 8; ++o) {
        float4 acc = {0.f, 0.f, 0.f, 0.f};
#pragma unroll
        for (int ky = 0; ky < 3; ++ky) {
            int si = o + ky;
            float w0 = w[ky * 3], w1_ = w[ky * 3 + 1], w2_ = w[ky * 3 + 2];
            float4 c = cv[si];
            acc.x += w0 * lv[si] + w1_ * c.x + w2_ * c.y;
            acc.y += w0 * c.x   + w1_ * c.y + w2_ * c.z;
            acc.z += w0 * c.y   + w1_ * c.z + w2_ * c.w;
            acc.w += w0 * c.z   + w1_ * c.w + w2_ * rv[si];
        }
        float* dst = oplane + (yb + o) * WW + x0;
        __builtin_nontemporal_store(acc.x, dst + 0);
        __builtin_nontemporal_store(acc.y, dst + 1);
        __builtin_nontemporal_store(acc.z, dst + 2);
        __builtin_nontemporal_store(acc.w, dst + 3);
    }
}

// ---------------------------------------------------------------------------
extern "C" void kernel_launch(void* const* d_in, const int* in_sizes, int n_in,
                              void* d_out, int out_size, void* d_ws, size_t ws_size,
                              hipStream_t stream) {
    const float* x  = (const float*)d_in[0];
    const float* w1 = (const float*)d_in[1];
    const float* b1 = (const float*)d_in[2];
    const float* w2 = (const float*)d_in[3];
    const float* b2 = (const float*)d_in[4];
    float* out = (float*)d_out;

    float* ws = (float*)d_ws;
    float* pooled = ws;          // B*C = 1024 floats
    float* kern   = ws + 1024;   // B*C*9 = 9216 floats

    pool_kernel<<<BB * CC, 512, 0, stream>>>(x, pooled);
    kerngen_kernel<<<BB * 9, 128, 0, stream>>>(pooled, w1, b1, w2, b2, kern);
    conv_kernel<<<BB * CC * 2, 256, 0, stream>>>(x, kern, out);
}